// Round 18
// baseline (78.136 us; speedup 1.0000x reference)
//
#include <hip/hip_runtime.h>

typedef __attribute__((ext_vector_type(8))) short short8;
typedef __attribute__((ext_vector_type(4))) float f32x4;
typedef __attribute__((ext_vector_type(4))) unsigned short ushort4_t;
typedef unsigned short ushort_t;
typedef unsigned long long u64;

#define D_MODEL 768
#define NHEAD 12
#define HD 64
#define BATCH 4
#define HWIDTH 32
#define HW 1024
#define TOK (BATCH*HW)
#define QKV_N (3*D_MODEL)
#define BH (BATCH*NHEAD)
#define QSCALE 0.18033688f  /* 0.125 * log2(e) */

__device__ __forceinline__ ushort_t f2bf(float f) {
    union { float f; unsigned u; } v; v.f = f;
    unsigned u = v.u;
    unsigned r = u + 0x7FFFu + ((u >> 16) & 1u);
    return (ushort_t)(r >> 16);
}
__device__ __forceinline__ float ex2(float x) {
    float r; asm("v_exp_f32 %0, %1" : "=v"(r) : "v"(x)); return r;
}
__device__ __forceinline__ unsigned cvtpk(float lo, float hi) {
    unsigned r; asm("v_cvt_pk_bf16_f32 %0, %1, %2" : "=v"(r) : "v"(lo), "v"(hi)); return r;
}

// ---------------- fused prep: rmsnorm | cvt(w_qkv) | cvt(w_out) | sincos ----------------
__global__ __launch_bounds__(256) void prep_kernel(const float* __restrict__ x,
                                                   const float* __restrict__ gamma,
                                                   ushort_t* __restrict__ xn,
                                                   const float* __restrict__ w_qkv,
                                                   ushort_t* __restrict__ wq,
                                                   const float* __restrict__ w_out,
                                                   ushort_t* __restrict__ wo,
                                                   float* __restrict__ sint,
                                                   float* __restrict__ cost) {
    int blk = blockIdx.x;
    if (blk < 1024) {
        int wave = threadIdx.x >> 6, lane = threadIdx.x & 63;
        int t = blk * 4 + wave;
        const float* xr = x + (size_t)t * D_MODEL;
        float v[12]; float ss = 0.f;
        #pragma unroll
        for (int j = 0; j < 12; ++j) { v[j] = xr[lane + j*64]; ss += v[j]*v[j]; }
        #pragma unroll
        for (int m = 1; m < 64; m <<= 1) ss += __shfl_xor(ss, m, 64);
        float r = rsqrtf(ss * (1.f/768.f) + 1e-6f);
        ushort_t* o = xn + (size_t)t * D_MODEL;
        #pragma unroll
        for (int j = 0; j < 12; ++j) o[lane + j*64] = f2bf(v[j] * r * gamma[lane + j*64]);
    } else if (blk < 2752) {
        int i = (blk - 1024) * 1024 + threadIdx.x * 4;
        float4 v = *(const float4*)&w_qkv[i];
        uint2 pk; pk.x = cvtpk(v.x, v.y); pk.y = cvtpk(v.z, v.w);
        *(uint2*)&wq[i] = pk;
    } else if (blk < 3328) {
        int i = (blk - 2752) * 1024 + threadIdx.x * 4;
        float4 v = *(const float4*)&w_out[i];
        uint2 pk; pk.x = cvtpk(v.x, v.y); pk.y = cvtpk(v.z, v.w);
        *(uint2*)&wo[i] = pk;
    } else {
        int i = (blk - 3328) * 256 + threadIdx.x;
        int p = i >> 5, j = i & 31;
        int r = p >> 5, c = p & 31;
        int jj = j & 15;
        float freq = powf(10000.f, -(float)(2*jj) / 32.f);
        float pos = (j < 16) ? (float)r : (float)c;
        float th = pos * freq;
        sint[i] = sinf(th);
        cost[i] = cosf(th);
    }
}

// ---------------- 128x128 GEMM, BK=64, 2 buffers, 1 barrier/step, depth-1 prefetch ----------------
template<int NTILES, int EPI>
__global__ __launch_bounds__(256, 2) void gemm128(const ushort_t* __restrict__ A,
                                                  const ushort_t* __restrict__ B,
                                                  const float* __restrict__ sint,
                                                  const float* __restrict__ cost,
                                                  ushort_t* __restrict__ Qr,
                                                  ushort_t* __restrict__ Kr,
                                                  ushort_t* __restrict__ VTt,
                                                  float* __restrict__ C) {
    __shared__ ushort_t As[2][128*64];
    __shared__ ushort_t Bs[2][128*64];
    const int K = 768;
    constexpr int NR = NTILES / 2;
    int c = blockIdx.x & 7;
    int l = blockIdx.x >> 3;
    int mtile = (c >> 1)*8 + l / NR;
    int ntile = (c & 1)*NR + l % NR;
    int tm = mtile * 128, tn = ntile * 128;
    int w = threadIdx.x >> 6, lane = threadIdx.x & 63;
    int wr = w >> 1, wc = w & 1;
    int l15 = lane & 15, l4 = lane >> 4;

    const ushort_t* mat = (w < 2) ? A : B;
    int mbase = (w < 2) ? tm : tn;
    ushort_t* lds_half = (w < 2) ? &As[0][0] : &Bs[0][0];
    int r0w = (w & 1) * 64;
    int srow = r0w + (lane >> 3);
    int sslot = (lane & 7) ^ (srow & 7);
    const ushort_t* gsrc0 = mat + (size_t)(mbase + srow)*K + sslot*8;

    auto stage = [&](int buf, int kstep) {
        int k0 = kstep * 64;
        #pragma unroll
        for (int j = 0; j < 8; ++j) {
            const ushort_t* g = gsrc0 + (size_t)(j*8)*K + k0;
            __builtin_amdgcn_global_load_lds((const __attribute__((address_space(1))) void*)g,
                (__attribute__((address_space(3))) void*)(lds_half + (size_t)buf*8192 + (r0w + j*8)*64),
                16, 0, 0);
        }
    };

    f32x4 acc[4][4] = {};
    auto compute = [&](int bi) {
        short8 af[4][2], bfx[4][2];
        #pragma unroll
        for (int mi = 0; mi < 4; ++mi) {
            int row = wr*64 + mi*16 + l15;
            #pragma unroll
            for (int kk = 0; kk < 2; ++kk)
                af[mi][kk] = *(const short8*)&As[bi][row*64 + ((kk*4 + l4) ^ (row & 7))*8];
        }
        #pragma unroll
        for (int ni = 0; ni < 4; ++ni) {
            int row = wc*64 + ni*16 + l15;
            #pragma unroll
            for (int kk = 0; kk < 2; ++kk)
                bfx[ni][kk] = *(const short8*)&Bs[bi][row*64 + ((kk*4 + l4) ^ (row & 7))*8];
        }
        #pragma unroll
        for (int kk = 0; kk < 2; ++kk)
            #pragma unroll
            for (int mi = 0; mi < 4; ++mi)
                #pragma unroll
                for (int ni = 0; ni < 4; ++ni)
                    acc[mi][ni] = __builtin_amdgcn_mfma_f32_16x16x32_bf16(af[mi][kk], bfx[ni][kk], acc[mi][ni], 0, 0, 0);
    };

    stage(0, 0);
    for (int t = 0; t < 12; ++t) {
        asm volatile("s_waitcnt vmcnt(0)" ::: "memory");
        __builtin_amdgcn_s_barrier();
        if (t < 11) stage((t + 1) & 1, t + 1);
        compute(t & 1);
    }

    if constexpr (EPI == 0) {
        int col_base = tn + wc*64;
        int region = col_base / 768;
        int h = (col_base % 768) >> 6;
        if (region < 2) {
            ushort_t* dst = (region == 0) ? Qr : Kr;
            float scale = (region == 0) ? QSCALE : 1.f;
            #pragma unroll
            for (int mi = 0; mi < 4; ++mi) {
                #pragma unroll
                for (int ni = 0; ni < 2; ++ni) {
                    int d = ni*16 + l15;
                    #pragma unroll
                    for (int r = 0; r < 4; ++r) {
                        int pt = tm + wr*64 + mi*16 + l4*4 + r;
                        int b = pt >> 10, p = pt & 1023;
                        float s = sint[p*32 + d], cc = cost[p*32 + d];
                        float t0 = acc[mi][ni][r], t1 = acc[mi][ni+2][r];
                        size_t o = (size_t)(b*NHEAD + h)*HW*HD + (size_t)p*HD + d;
                        dst[o]      = f2bf((t0*cc - t1*s) * scale);
                        dst[o + 32] = f2bf((t1*cc + t0*s) * scale);
                    }
                }
            }
        } else {
            #pragma unroll
            for (int mi = 0; mi < 4; ++mi) {
                int pt = tm + wr*64 + mi*16 + l4*4;
                int b = pt >> 10, p = pt & 1023;
                size_t hb = (size_t)(b*NHEAD + h)*HD*HW;
                #pragma unroll
                for (int ni = 0; ni < 4; ++ni) {
                    int d = ni*16 + l15;
                    ushort4_t pk;
                    pk.x = f2bf(acc[mi][ni][0]);
                    pk.y = f2bf(acc[mi][ni][1]);
                    pk.z = f2bf(acc[mi][ni][2]);
                    pk.w = f2bf(acc[mi][ni][3]);
                    *(ushort4_t*)&VTt[hb + (size_t)d*HW + p] = pk;
                }
            }
        }
    } else {
        #pragma unroll
        for (int mi = 0; mi < 4; ++mi)
            #pragma unroll
            for (int ni = 0; ni < 4; ++ni)
                #pragma unroll
                for (int r = 0; r < 4; ++r) {
                    int row = tm + wr*64 + mi*16 + l4*4 + r;
                    int col = tn + wc*64 + ni*16 + l15;
                    C[(size_t)row*(128*NTILES) + col] = acc[mi][ni][r];
                }
    }
}

// ---------------- flash attention: T15 ping-pong pipeline (QK^T(t+1) between softmax(t) and PV(t)) ----------------
// grid 768 (16 qtiles x 48 bh, XCD-swizzled); 4 waves; wave: 16 q, kv tiles of 64; tile k in buf k&1
__global__ __launch_bounds__(256, 3) void attn_kernel(const ushort_t* __restrict__ Q,
                                                      const ushort_t* __restrict__ Kt,
                                                      const ushort_t* __restrict__ VT,
                                                      ushort_t* __restrict__ Ao) {
    __shared__ ushort_t Kb[2][64*64];
    __shared__ ushort_t Vb[2][64*64];
    __shared__ ushort_t P[4][16][72];
    int flat = blockIdx.x;
    int swz = (flat & 7) * 96 + (flat >> 3);
    int bh = swz >> 4;
    int qtile = swz & 15;
    int w = threadIdx.x >> 6, lane = threadIdx.x & 63;
    int l15 = lane & 15, l4 = lane >> 4;
    int qbase = qtile * 64 + w * 16;
    int q = qbase + l15;
    int qr = q >> 5, qc = q & 31;
    const ushort_t* Qh = Q + (size_t)bh * HW * HD;
    const ushort_t* Kh = Kt + (size_t)bh * HW * HD;
    const ushort_t* Vh = VT + (size_t)bh * HD * HW;
    short8 aq0 = *(const short8*)&Qh[(size_t)q*64 + l4*8];
    short8 aq1 = *(const short8*)&Qh[(size_t)q*64 + 32 + l4*8];
    unsigned pat = (qc == 0) ? 3u : (7u << (qc - 1));
    int sw = l15 & 7;
    float m = -1e30f, lsum = 0.f;
    f32x4 oacc[4] = {};

    auto stage = [&](int bufi, int kv) {
        #pragma unroll
        for (int is = 0; is < 2; ++is) {
            int c = is*256 + w*64 + lane;
            int row = c >> 3;
            int col16 = (c & 7) ^ (row & 7);
            const ushort_t* ga = Kh + (size_t)(kv + row)*64 + col16*8;
            __builtin_amdgcn_global_load_lds((const __attribute__((address_space(1))) void*)ga,
                (__attribute__((address_space(3))) void*)(&Kb[bufi][(size_t)(is*256 + w*64)*8]), 16, 0, 0);
            const ushort_t* gv = Vh + (size_t)row*HW + kv + col16*8;
            __builtin_amdgcn_global_load_lds((const __attribute__((address_space(1))) void*)gv,
                (__attribute__((address_space(3))) void*)(&Vb[bufi][(size_t)(is*256 + w*64)*8]), 16, 0, 0);
        }
    };

    // QK^T for buffer buf -> s
    auto ldK = [&](int buf, f32x4 (&s)[4]) {
        __builtin_amdgcn_s_setprio(1);
        #pragma unroll
        for (int st = 0; st < 4; ++st) {
            int krow = st*16 + l15;
            short8 bk0 = *(const short8*)&Kb[buf][(size_t)krow*64 + (size_t)((l4 ^ sw))*8];
            short8 bk1 = *(const short8*)&Kb[buf][(size_t)krow*64 + (size_t)(((4+l4) ^ sw))*8];
            f32x4 z = {};
            z = __builtin_amdgcn_mfma_f32_16x16x32_bf16(bk0, aq0, z, 0, 0, 0);
            z = __builtin_amdgcn_mfma_f32_16x16x32_bf16(bk1, aq1, z, 0, 0, 0);
            s[st] = z;
        }
        __builtin_amdgcn_s_setprio(0);
    };
    auto ldV = [&](int buf, short8 (&va0)[4], short8 (&va1)[4]) {
        #pragma unroll
        for (int dt = 0; dt < 4; ++dt) {
            int vrow = dt*16 + l15;
            va0[dt] = *(const short8*)&Vb[buf][(size_t)vrow*64 + (size_t)((l4 ^ sw))*8];
            va1[dt] = *(const short8*)&Vb[buf][(size_t)vrow*64 + (size_t)(((4+l4) ^ sw))*8];
        }
    };

    // softmax(t) -> [pipe: drain; barrier; stage(t+2); QK^T(t+1)->sn; V(t+1)->vn] -> PV(t)
    auto tile_step = [&](f32x4 (&s)[4], short8 (&va0)[4], short8 (&va1)[4],
                         f32x4 (&sn)[4], short8 (&vn0)[4], short8 (&vn1)[4], int t) {
        int kv = t * 64;
        // ---- mask ----
        int dr = qr - (kv >> 5);
        if (dr >= -1 && dr <= 2) {
            u64 tm = 0;
            if (dr <= 1) tm |= (u64)pat;
            if (dr >= 0) tm |= ((u64)pat) << 32;
            u64 sub = tm >> (l4*4);
            #pragma unroll
            for (int st = 0; st < 4; ++st)
                #pragma unroll
                for (int i = 0; i < 4; ++i)
                    if ((sub >> (st*16 + i)) & 1) s[st][i] = -1e30f;
        }
        // ---- running max (log2 domain), deferred rescale ----
        float vmax = fmaxf(
            fmaxf(fmaxf(fmaxf(s[0][0], s[0][1]), fmaxf(s[0][2], s[0][3])),
                  fmaxf(fmaxf(s[1][0], s[1][1]), fmaxf(s[1][2], s[1][3]))),
            fmaxf(fmaxf(fmaxf(s[2][0], s[2][1]), fmaxf(s[2][2], s[2][3])),
                  fmaxf(fmaxf(s[3][0], s[3][1]), fmaxf(s[3][2], s[3][3]))));
        vmax = fmaxf(vmax, __shfl_xor(vmax, 16, 64));
        vmax = fmaxf(vmax, __shfl_xor(vmax, 32, 64));
        if (__any(vmax - m > 8.f)) {
            float mn = fmaxf(m, vmax);
            float sf = ex2(m - mn);
            lsum *= sf;
            #pragma unroll
            for (int dt = 0; dt < 4; ++dt)
                #pragma unroll
                for (int i = 0; i < 4; ++i) oacc[dt][i] *= sf;
            m = mn;
        }
        // ---- P = 2^(s-m), row-sum, pack bf16 ----
        float ls = 0.f;
        #pragma unroll
        for (int st = 0; st < 4; ++st) {
            float p0 = ex2(s[st][0] - m), p1 = ex2(s[st][1] - m);
            float p2 = ex2(s[st][2] - m), p3 = ex2(s[st][3] - m);
            ls += (p0 + p1) + (p2 + p3);
            uint2 pk;
            pk.x = cvtpk(p0, p1);
            pk.y = cvtpk(p2, p3);
            *(uint2*)&P[w][l15][st*16 + l4*4] = pk;
        }
        ls += __shfl_xor(ls, 16, 64);
        ls += __shfl_xor(ls, 32, 64);
        lsum += ls;
        short8 pf0 = *(const short8*)&P[w][l15][l4*8];
        short8 pf1 = *(const short8*)&P[w][l15][32 + l4*8];
        // ---- pipe: next tile's QK^T issued before this tile's PV ----
        if (t < 15) {
            asm volatile("s_waitcnt vmcnt(0) lgkmcnt(0)" ::: "memory");
            __builtin_amdgcn_s_barrier();          // stage(t+1) landed; all waves' buf-(t&1) reads drained
            if (t < 14) stage(t & 1, (t + 2) * 64);
            ldK((t + 1) & 1, sn);                  // QK^T(t+1): MFMA issues now
            ldV((t + 1) & 1, vn0, vn1);
        }
        // ---- PV(t): overlaps with next iteration's softmax on the VALU ----
        __builtin_amdgcn_s_setprio(1);
        #pragma unroll
        for (int dt = 0; dt < 4; ++dt) {
            oacc[dt] = __builtin_amdgcn_mfma_f32_16x16x32_bf16(va0[dt], pf0, oacc[dt], 0, 0, 0);
            oacc[dt] = __builtin_amdgcn_mfma_f32_16x16x32_bf16(va1[dt], pf1, oacc[dt], 0, 0, 0);
        }
        __builtin_amdgcn_s_setprio(0);
    };

    // prologue: tile 0 staged, computed into set A; tile 1 staged
    stage(0, 0);
    asm volatile("s_waitcnt vmcnt(0)" ::: "memory");
    __builtin_amdgcn_s_barrier();
    stage(1, 64);
    f32x4 sA[4], sB[4];
    short8 vA0[4], vA1[4], vB0[4], vB1[4];
    ldK(0, sA);
    ldV(0, vA0, vA1);

    for (int it = 0; it < 8; ++it) {
        tile_step(sA, vA0, vA1, sB, vB0, vB1, 2*it);
        tile_step(sB, vB0, vB1, sA, vA0, vA1, 2*it + 1);
    }

    int b = bh / NHEAD, h = bh % NHEAD;
    float rl = 1.f / lsum;
    size_t obase = ((size_t)b*HW + q)*D_MODEL + h*64;
    #pragma unroll
    for (int dt = 0; dt < 4; ++dt) {
        uint2 pk;
        pk.x = cvtpk(oacc[dt][0]*rl, oacc[dt][1]*rl);
        pk.y = cvtpk(oacc[dt][2]*rl, oacc[dt][3]*rl);
        *(uint2*)&Ao[obase + dt*16 + l4*4] = pk;
    }
}

extern "C" void kernel_launch(void* const* d_in, const int* in_sizes, int n_in,
                              void* d_out, int out_size, void* d_ws, size_t ws_size,
                              hipStream_t stream) {
    const float* x      = (const float*)d_in[0];
    const float* w_qkv  = (const float*)d_in[1];
    const float* w_out  = (const float*)d_in[2];
    const float* gamma  = (const float*)d_in[3];
    float* out = (float*)d_out;

    char* ws = (char*)d_ws;
    size_t off = 0;
    auto alloc = [&](size_t bytes) { char* p = ws + off; off += (bytes + 255) & ~255ull; return p; };
    ushort_t* xn   = (ushort_t*)alloc((size_t)TOK*D_MODEL*2);
    ushort_t* wq   = (ushort_t*)alloc((size_t)QKV_N*D_MODEL*2);
    ushort_t* wo   = (ushort_t*)alloc((size_t)D_MODEL*D_MODEL*2);
    float* sint    = (float*)alloc((size_t)HW*32*4);
    float* cost    = (float*)alloc((size_t)HW*32*4);
    ushort_t* Qr   = (ushort_t*)alloc((size_t)BH*HW*HD*2);
    ushort_t* Kr   = (ushort_t*)alloc((size_t)BH*HW*HD*2);
    ushort_t* VTt  = (ushort_t*)alloc((size_t)BH*HD*HW*2);
    ushort_t* Ao   = (ushort_t*)alloc((size_t)TOK*D_MODEL*2);

    prep_kernel<<<3456, 256, 0, stream>>>(x, gamma, xn, w_qkv, wq, w_out, wo, sint, cost);
    gemm128<18,0><<<576, 256, 0, stream>>>(xn, wq, sint, cost, Qr, Kr, VTt, nullptr);
    attn_kernel<<<768, 256, 0, stream>>>(Qr, Kr, VTt, Ao);
    gemm128<6,1><<<192, 256, 0, stream>>>(Ao, wo, nullptr, nullptr, nullptr, nullptr, nullptr, out);
}

// Round 19
// 73.584 us; speedup vs baseline: 1.0619x; 1.0619x over previous
//
#include <hip/hip_runtime.h>

typedef __attribute__((ext_vector_type(8))) short short8;
typedef __attribute__((ext_vector_type(4))) float f32x4;
typedef __attribute__((ext_vector_type(4))) unsigned short ushort4_t;
typedef unsigned short ushort_t;
typedef unsigned long long u64;

#define D_MODEL 768
#define NHEAD 12
#define HD 64
#define BATCH 4
#define HWIDTH 32
#define HW 1024
#define TOK (BATCH*HW)
#define QKV_N (3*D_MODEL)
#define BH (BATCH*NHEAD)
#define QSCALE 0.18033688f  /* 0.125 * log2(e) */

__device__ __forceinline__ ushort_t f2bf(float f) {
    union { float f; unsigned u; } v; v.f = f;
    unsigned u = v.u;
    unsigned r = u + 0x7FFFu + ((u >> 16) & 1u);
    return (ushort_t)(r >> 16);
}
__device__ __forceinline__ float ex2(float x) {
    float r; asm("v_exp_f32 %0, %1" : "=v"(r) : "v"(x)); return r;
}
__device__ __forceinline__ unsigned cvtpk(float lo, float hi) {
    unsigned r; asm("v_cvt_pk_bf16_f32 %0, %1, %2" : "=v"(r) : "v"(lo), "v"(hi)); return r;
}

// ---------------- fused prep: rmsnorm | cvt(w_qkv) | cvt(w_out) | sincos ----------------
__global__ __launch_bounds__(256) void prep_kernel(const float* __restrict__ x,
                                                   const float* __restrict__ gamma,
                                                   ushort_t* __restrict__ xn,
                                                   const float* __restrict__ w_qkv,
                                                   ushort_t* __restrict__ wq,
                                                   const float* __restrict__ w_out,
                                                   ushort_t* __restrict__ wo,
                                                   float* __restrict__ sint,
                                                   float* __restrict__ cost) {
    int blk = blockIdx.x;
    if (blk < 1024) {
        int wave = threadIdx.x >> 6, lane = threadIdx.x & 63;
        int t = blk * 4 + wave;
        const float* xr = x + (size_t)t * D_MODEL;
        float v[12]; float ss = 0.f;
        #pragma unroll
        for (int j = 0; j < 12; ++j) { v[j] = xr[lane + j*64]; ss += v[j]*v[j]; }
        #pragma unroll
        for (int m = 1; m < 64; m <<= 1) ss += __shfl_xor(ss, m, 64);
        float r = rsqrtf(ss * (1.f/768.f) + 1e-6f);
        ushort_t* o = xn + (size_t)t * D_MODEL;
        #pragma unroll
        for (int j = 0; j < 12; ++j) o[lane + j*64] = f2bf(v[j] * r * gamma[lane + j*64]);
    } else if (blk < 2752) {
        int i = (blk - 1024) * 1024 + threadIdx.x * 4;
        float4 v = *(const float4*)&w_qkv[i];
        uint2 pk; pk.x = cvtpk(v.x, v.y); pk.y = cvtpk(v.z, v.w);
        *(uint2*)&wq[i] = pk;
    } else if (blk < 3328) {
        int i = (blk - 2752) * 1024 + threadIdx.x * 4;
        float4 v = *(const float4*)&w_out[i];
        uint2 pk; pk.x = cvtpk(v.x, v.y); pk.y = cvtpk(v.z, v.w);
        *(uint2*)&wo[i] = pk;
    } else {
        int i = (blk - 3328) * 256 + threadIdx.x;
        int p = i >> 5, j = i & 31;
        int r = p >> 5, c = p & 31;
        int jj = j & 15;
        float freq = powf(10000.f, -(float)(2*jj) / 32.f);
        float pos = (j < 16) ? (float)r : (float)c;
        float th = pos * freq;
        sint[i] = sinf(th);
        cost[i] = cosf(th);
    }
}

// ---------------- 128x128 GEMM, BK=64, 2 buffers, 1 barrier/step, depth-1 prefetch ----------------
// (qkv GEMM with fused RoPE / V-transpose epilogue)
__global__ __launch_bounds__(256, 2) void gemm_qkv(const ushort_t* __restrict__ A,
                                                   const ushort_t* __restrict__ B,
                                                   const float* __restrict__ sint,
                                                   const float* __restrict__ cost,
                                                   ushort_t* __restrict__ Qr,
                                                   ushort_t* __restrict__ Kr,
                                                   ushort_t* __restrict__ VTt) {
    __shared__ ushort_t As[2][128*64];
    __shared__ ushort_t Bs[2][128*64];
    const int K = 768;
    constexpr int NR = 9;                // 18 ntiles / 2 chunks
    int c = blockIdx.x & 7;
    int l = blockIdx.x >> 3;
    int mtile = (c >> 1)*8 + l / NR;
    int ntile = (c & 1)*NR + l % NR;
    int tm = mtile * 128, tn = ntile * 128;
    int w = threadIdx.x >> 6, lane = threadIdx.x & 63;
    int wr = w >> 1, wc = w & 1;
    int l15 = lane & 15, l4 = lane >> 4;

    const ushort_t* mat = (w < 2) ? A : B;
    int mbase = (w < 2) ? tm : tn;
    ushort_t* lds_half = (w < 2) ? &As[0][0] : &Bs[0][0];
    int r0w = (w & 1) * 64;
    int srow = r0w + (lane >> 3);
    int sslot = (lane & 7) ^ (srow & 7);
    const ushort_t* gsrc0 = mat + (size_t)(mbase + srow)*K + sslot*8;

    auto stage = [&](int buf, int kstep) {
        int k0 = kstep * 64;
        #pragma unroll
        for (int j = 0; j < 8; ++j) {
            const ushort_t* g = gsrc0 + (size_t)(j*8)*K + k0;
            __builtin_amdgcn_global_load_lds((const __attribute__((address_space(1))) void*)g,
                (__attribute__((address_space(3))) void*)(lds_half + (size_t)buf*8192 + (r0w + j*8)*64),
                16, 0, 0);
        }
    };

    f32x4 acc[4][4] = {};
    auto compute = [&](int bi) {
        short8 af[4][2], bfx[4][2];
        #pragma unroll
        for (int mi = 0; mi < 4; ++mi) {
            int row = wr*64 + mi*16 + l15;
            #pragma unroll
            for (int kk = 0; kk < 2; ++kk)
                af[mi][kk] = *(const short8*)&As[bi][row*64 + ((kk*4 + l4) ^ (row & 7))*8];
        }
        #pragma unroll
        for (int ni = 0; ni < 4; ++ni) {
            int row = wc*64 + ni*16 + l15;
            #pragma unroll
            for (int kk = 0; kk < 2; ++kk)
                bfx[ni][kk] = *(const short8*)&Bs[bi][row*64 + ((kk*4 + l4) ^ (row & 7))*8];
        }
        #pragma unroll
        for (int kk = 0; kk < 2; ++kk)
            #pragma unroll
            for (int mi = 0; mi < 4; ++mi)
                #pragma unroll
                for (int ni = 0; ni < 4; ++ni)
                    acc[mi][ni] = __builtin_amdgcn_mfma_f32_16x16x32_bf16(af[mi][kk], bfx[ni][kk], acc[mi][ni], 0, 0, 0);
    };

    stage(0, 0);
    for (int t = 0; t < 12; ++t) {
        asm volatile("s_waitcnt vmcnt(0)" ::: "memory");
        __builtin_amdgcn_s_barrier();
        if (t < 11) stage((t + 1) & 1, t + 1);
        compute(t & 1);
    }

    int col_base = tn + wc*64;
    int region = col_base / 768;
    int h = (col_base % 768) >> 6;
    if (region < 2) {
        ushort_t* dst = (region == 0) ? Qr : Kr;
        float scale = (region == 0) ? QSCALE : 1.f;
        #pragma unroll
        for (int mi = 0; mi < 4; ++mi) {
            #pragma unroll
            for (int ni = 0; ni < 2; ++ni) {
                int d = ni*16 + l15;
                #pragma unroll
                for (int r = 0; r < 4; ++r) {
                    int pt = tm + wr*64 + mi*16 + l4*4 + r;
                    int b = pt >> 10, p = pt & 1023;
                    float s = sint[p*32 + d], cc = cost[p*32 + d];
                    float t0 = acc[mi][ni][r], t1 = acc[mi][ni+2][r];
                    size_t o = (size_t)(b*NHEAD + h)*HW*HD + (size_t)p*HD + d;
                    dst[o]      = f2bf((t0*cc - t1*s) * scale);
                    dst[o + 32] = f2bf((t1*cc + t0*s) * scale);
                }
            }
        }
    } else {
        #pragma unroll
        for (int mi = 0; mi < 4; ++mi) {
            int pt = tm + wr*64 + mi*16 + l4*4;
            int b = pt >> 10, p = pt & 1023;
            size_t hb = (size_t)(b*NHEAD + h)*HD*HW;
            #pragma unroll
            for (int ni = 0; ni < 4; ++ni) {
                int d = ni*16 + l15;
                ushort4_t pk;
                pk.x = f2bf(acc[mi][ni][0]);
                pk.y = f2bf(acc[mi][ni][1]);
                pk.z = f2bf(acc[mi][ni][2]);
                pk.w = f2bf(acc[mi][ni][3]);
                *(ushort4_t*)&VTt[hb + (size_t)d*HW + p] = pk;
            }
        }
    }
}

// ---------------- out-proj GEMM: 128x64 tiles, grid 384 (1.5 blocks/CU), same pipeline ----------------
// C[4096,768] = A[4096,768] * B[768,768]^T. 4 waves = 4 x 32-row slabs x 64 cols.
__global__ __launch_bounds__(256, 2) void gemm_out(const ushort_t* __restrict__ A,
                                                   const ushort_t* __restrict__ B,
                                                   float* __restrict__ C) {
    __shared__ ushort_t As[2][128*64];   // 32 KB
    __shared__ ushort_t Bs[2][64*64];    // 16 KB
    const int K = 768;
    int c = blockIdx.x & 7;
    int l = blockIdx.x >> 3;             // 0..47
    int mtile = (c >> 1)*8 + l / 6;      // 0..31
    int ntile = (c & 1)*6 + l % 6;       // 0..11
    int tm = mtile * 128, tn = ntile * 64;
    int w = threadIdx.x >> 6, lane = threadIdx.x & 63;
    int l15 = lane & 15, l4 = lane >> 4;

    // staging: waves 0,1 -> A 64-row halves; wave 2 -> B (64 rows); wave 3 idle
    int r0w = (w & 1) * 64;
    int srow_a = r0w + (lane >> 3);
    int sslot = (lane & 7) ^ (srow_a & 7);
    const ushort_t* gA = A + (size_t)(tm + srow_a)*K + sslot*8;
    int srow_b = lane >> 3;
    int sslot_b = (lane & 7) ^ (srow_b & 7);
    const ushort_t* gB = B + (size_t)(tn + srow_b)*K + sslot_b*8;

    auto stage = [&](int buf, int kstep) {
        int k0 = kstep * 64;
        if (w < 2) {
            #pragma unroll
            for (int j = 0; j < 8; ++j) {
                const ushort_t* g = gA + (size_t)(j*8)*K + k0;
                __builtin_amdgcn_global_load_lds((const __attribute__((address_space(1))) void*)g,
                    (__attribute__((address_space(3))) void*)(&As[buf][(r0w + j*8)*64]), 16, 0, 0);
            }
        } else if (w == 2) {
            #pragma unroll
            for (int j = 0; j < 8; ++j) {
                const ushort_t* g = gB + (size_t)(j*8)*K + k0;
                __builtin_amdgcn_global_load_lds((const __attribute__((address_space(1))) void*)g,
                    (__attribute__((address_space(3))) void*)(&Bs[buf][(j*8)*64]), 16, 0, 0);
            }
        }
    };

    f32x4 acc[2][4] = {};
    auto compute = [&](int bi) {
        short8 af[2][2], bfx[4][2];
        #pragma unroll
        for (int mi = 0; mi < 2; ++mi) {
            int row = w*32 + mi*16 + l15;
            #pragma unroll
            for (int kk = 0; kk < 2; ++kk)
                af[mi][kk] = *(const short8*)&As[bi][row*64 + ((kk*4 + l4) ^ (row & 7))*8];
        }
        #pragma unroll
        for (int ni = 0; ni < 4; ++ni) {
            int row = ni*16 + l15;
            #pragma unroll
            for (int kk = 0; kk < 2; ++kk)
                bfx[ni][kk] = *(const short8*)&Bs[bi][row*64 + ((kk*4 + l4) ^ (row & 7))*8];
        }
        #pragma unroll
        for (int kk = 0; kk < 2; ++kk)
            #pragma unroll
            for (int mi = 0; mi < 2; ++mi)
                #pragma unroll
                for (int ni = 0; ni < 4; ++ni)
                    acc[mi][ni] = __builtin_amdgcn_mfma_f32_16x16x32_bf16(af[mi][kk], bfx[ni][kk], acc[mi][ni], 0, 0, 0);
    };

    stage(0, 0);
    for (int t = 0; t < 12; ++t) {
        asm volatile("s_waitcnt vmcnt(0)" ::: "memory");
        __builtin_amdgcn_s_barrier();
        if (t < 11) stage((t + 1) & 1, t + 1);
        compute(t & 1);
    }

    #pragma unroll
    for (int mi = 0; mi < 2; ++mi)
        #pragma unroll
        for (int ni = 0; ni < 4; ++ni)
            #pragma unroll
            for (int r = 0; r < 4; ++r) {
                int row = tm + w*32 + mi*16 + l4*4 + r;
                int col = tn + ni*16 + l15;
                C[(size_t)row*D_MODEL + col] = acc[mi][ni][r];
            }
}

// ---------------- flash attention: LDS-staged, 1 barrier/tile, depth-1 prefetch (R16) ----------------
// grid 768 (16 qtiles x 48 bh, XCD-swizzled); 4 waves; wave: 16 q, kv tiles of 64
__global__ __launch_bounds__(256, 3) void attn_kernel(const ushort_t* __restrict__ Q,
                                                      const ushort_t* __restrict__ Kt,
                                                      const ushort_t* __restrict__ VT,
                                                      ushort_t* __restrict__ Ao) {
    __shared__ ushort_t Kb[2][64*64];
    __shared__ ushort_t Vb[2][64*64];
    __shared__ ushort_t P[4][16][72];
    int flat = blockIdx.x;
    int swz = (flat & 7) * 96 + (flat >> 3);
    int bh = swz >> 4;
    int qtile = swz & 15;
    int w = threadIdx.x >> 6, lane = threadIdx.x & 63;
    int l15 = lane & 15, l4 = lane >> 4;
    int qbase = qtile * 64 + w * 16;
    int q = qbase + l15;
    int qr = q >> 5, qc = q & 31;
    const ushort_t* Qh = Q + (size_t)bh * HW * HD;
    const ushort_t* Kh = Kt + (size_t)bh * HW * HD;
    const ushort_t* Vh = VT + (size_t)bh * HD * HW;
    short8 aq0 = *(const short8*)&Qh[(size_t)q*64 + l4*8];
    short8 aq1 = *(const short8*)&Qh[(size_t)q*64 + 32 + l4*8];
    unsigned pat = (qc == 0) ? 3u : (7u << (qc - 1));
    float m = -1e30f, lsum = 0.f;
    f32x4 oacc[4] = {};

    auto stage = [&](int bufi, int kv) {
        #pragma unroll
        for (int is = 0; is < 2; ++is) {
            int c = is*256 + w*64 + lane;
            int row = c >> 3;
            int col16 = (c & 7) ^ (row & 7);
            const ushort_t* ga = Kh + (size_t)(kv + row)*64 + col16*8;
            __builtin_amdgcn_global_load_lds((const __attribute__((address_space(1))) void*)ga,
                (__attribute__((address_space(3))) void*)(&Kb[bufi][(size_t)(is*256 + w*64)*8]), 16, 0, 0);
            const ushort_t* gv = Vh + (size_t)row*HW + kv + col16*8;
            __builtin_amdgcn_global_load_lds((const __attribute__((address_space(1))) void*)gv,
                (__attribute__((address_space(3))) void*)(&Vb[bufi][(size_t)(is*256 + w*64)*8]), 16, 0, 0);
        }
    };

    stage(0, 0);

    for (int t = 0; t < 16; ++t) {
        asm volatile("s_waitcnt vmcnt(0)" ::: "memory");
        __builtin_amdgcn_s_barrier();
        if (t < 15) stage((t + 1) & 1, (t + 1) * 64);
        int cur = t & 1;
        int kv = t * 64;
        int sw = l15 & 7;
        f32x4 s[4];
        __builtin_amdgcn_s_setprio(1);
        #pragma unroll
        for (int st = 0; st < 4; ++st) {
            int krow = st*16 + l15;
            short8 bk0 = *(const short8*)&Kb[cur][(size_t)krow*64 + (size_t)((l4 ^ sw))*8];
            short8 bk1 = *(const short8*)&Kb[cur][(size_t)krow*64 + (size_t)(((4+l4) ^ sw))*8];
            f32x4 z = {};
            z = __builtin_amdgcn_mfma_f32_16x16x32_bf16(bk0, aq0, z, 0, 0, 0);
            z = __builtin_amdgcn_mfma_f32_16x16x32_bf16(bk1, aq1, z, 0, 0, 0);
            s[st] = z;
        }
        __builtin_amdgcn_s_setprio(0);
        short8 va0[4], va1[4];
        #pragma unroll
        for (int dt = 0; dt < 4; ++dt) {
            int vrow = dt*16 + l15;
            va0[dt] = *(const short8*)&Vb[cur][(size_t)vrow*64 + (size_t)((l4 ^ sw))*8];
            va1[dt] = *(const short8*)&Vb[cur][(size_t)vrow*64 + (size_t)(((4+l4) ^ sw))*8];
        }
        int dr = qr - (kv >> 5);
        if (dr >= -1 && dr <= 2) {
            u64 tm = 0;
            if (dr <= 1) tm |= (u64)pat;
            if (dr >= 0) tm |= ((u64)pat) << 32;
            u64 sub = tm >> (l4*4);
            #pragma unroll
            for (int st = 0; st < 4; ++st)
                #pragma unroll
                for (int i = 0; i < 4; ++i)
                    if ((sub >> (st*16 + i)) & 1) s[st][i] = -1e30f;
        }
        float vmax = fmaxf(
            fmaxf(fmaxf(fmaxf(s[0][0], s[0][1]), fmaxf(s[0][2], s[0][3])),
                  fmaxf(fmaxf(s[1][0], s[1][1]), fmaxf(s[1][2], s[1][3]))),
            fmaxf(fmaxf(fmaxf(s[2][0], s[2][1]), fmaxf(s[2][2], s[2][3])),
                  fmaxf(fmaxf(s[3][0], s[3][1]), fmaxf(s[3][2], s[3][3]))));
        vmax = fmaxf(vmax, __shfl_xor(vmax, 16, 64));
        vmax = fmaxf(vmax, __shfl_xor(vmax, 32, 64));
        if (__any(vmax - m > 8.f)) {
            float mn = fmaxf(m, vmax);
            float sf = ex2(m - mn);
            lsum *= sf;
            #pragma unroll
            for (int dt = 0; dt < 4; ++dt)
                #pragma unroll
                for (int i = 0; i < 4; ++i) oacc[dt][i] *= sf;
            m = mn;
        }
        float ls = 0.f;
        #pragma unroll
        for (int st = 0; st < 4; ++st) {
            float p0 = ex2(s[st][0] - m), p1 = ex2(s[st][1] - m);
            float p2 = ex2(s[st][2] - m), p3 = ex2(s[st][3] - m);
            ls += (p0 + p1) + (p2 + p3);
            uint2 pk;
            pk.x = cvtpk(p0, p1);
            pk.y = cvtpk(p2, p3);
            *(uint2*)&P[w][l15][st*16 + l4*4] = pk;
        }
        ls += __shfl_xor(ls, 16, 64);
        ls += __shfl_xor(ls, 32, 64);
        lsum += ls;
        short8 pf0 = *(const short8*)&P[w][l15][l4*8];
        short8 pf1 = *(const short8*)&P[w][l15][32 + l4*8];
        __builtin_amdgcn_s_setprio(1);
        #pragma unroll
        for (int dt = 0; dt < 4; ++dt) {
            oacc[dt] = __builtin_amdgcn_mfma_f32_16x16x32_bf16(va0[dt], pf0, oacc[dt], 0, 0, 0);
            oacc[dt] = __builtin_amdgcn_mfma_f32_16x16x32_bf16(va1[dt], pf1, oacc[dt], 0, 0, 0);
        }
        __builtin_amdgcn_s_setprio(0);
    }
    int b = bh / NHEAD, h = bh % NHEAD;
    float rl = 1.f / lsum;
    size_t obase = ((size_t)b*HW + q)*D_MODEL + h*64;
    #pragma unroll
    for (int dt = 0; dt < 4; ++dt) {
        uint2 pk;
        pk.x = cvtpk(oacc[dt][0]*rl, oacc[dt][1]*rl);
        pk.y = cvtpk(oacc[dt][2]*rl, oacc[dt][3]*rl);
        *(uint2*)&Ao[obase + dt*16 + l4*4] = pk;
    }
}

extern "C" void kernel_launch(void* const* d_in, const int* in_sizes, int n_in,
                              void* d_out, int out_size, void* d_ws, size_t ws_size,
                              hipStream_t stream) {
    const float* x      = (const float*)d_in[0];
    const float* w_qkv  = (const float*)d_in[1];
    const float* w_out  = (const float*)d_in[2];
    const float* gamma  = (const float*)d_in[3];
    float* out = (float*)d_out;

    char* ws = (char*)d_ws;
    size_t off = 0;
    auto alloc = [&](size_t bytes) { char* p = ws + off; off += (bytes + 255) & ~255ull; return p; };
    ushort_t* xn   = (ushort_t*)alloc((size_t)TOK*D_MODEL*2);
    ushort_t* wq   = (ushort_t*)alloc((size_t)QKV_N*D_MODEL*2);
    ushort_t* wo   = (ushort_t*)alloc((size_t)D_MODEL*D_MODEL*2);
    float* sint    = (float*)alloc((size_t)HW*32*4);
    float* cost    = (float*)alloc((size_t)HW*32*4);
    ushort_t* Qr   = (ushort_t*)alloc((size_t)BH*HW*HD*2);
    ushort_t* Kr   = (ushort_t*)alloc((size_t)BH*HW*HD*2);
    ushort_t* VTt  = (ushort_t*)alloc((size_t)BH*HD*HW*2);
    ushort_t* Ao   = (ushort_t*)alloc((size_t)TOK*D_MODEL*2);

    prep_kernel<<<3456, 256, 0, stream>>>(x, gamma, xn, w_qkv, wq, w_out, wo, sint, cost);
    gemm_qkv<<<576, 256, 0, stream>>>(xn, wq, sint, cost, Qr, Kr, VTt);
    attn_kernel<<<768, 256, 0, stream>>>(Qr, Kr, VTt, Ao);
    gemm_out<<<384, 256, 0, stream>>>(Ao, wo, out);
}

// Round 21
// 72.169 us; speedup vs baseline: 1.0827x; 1.0196x over previous
//
#include <hip/hip_runtime.h>

typedef __attribute__((ext_vector_type(8))) short short8;
typedef __attribute__((ext_vector_type(4))) float f32x4;
typedef __attribute__((ext_vector_type(4))) unsigned short ushort4_t;
typedef unsigned short ushort_t;
typedef unsigned long long u64;

#define D_MODEL 768
#define NHEAD 12
#define HD 64
#define BATCH 4
#define HWIDTH 32
#define HW 1024
#define TOK (BATCH*HW)
#define QKV_N (3*D_MODEL)
#define BH (BATCH*NHEAD)
#define QSCALE 0.18033688f  /* 0.125 * log2(e) */

__device__ __forceinline__ ushort_t f2bf(float f) {
    union { float f; unsigned u; } v; v.f = f;
    unsigned u = v.u;
    unsigned r = u + 0x7FFFu + ((u >> 16) & 1u);
    return (ushort_t)(r >> 16);
}
__device__ __forceinline__ float ex2(float x) {
    float r; asm("v_exp_f32 %0, %1" : "=v"(r) : "v"(x)); return r;
}
__device__ __forceinline__ unsigned cvtpk(float lo, float hi) {
    unsigned r; asm("v_cvt_pk_bf16_f32 %0, %1, %2" : "=v"(r) : "v"(lo), "v"(hi)); return r;
}

// ---------------- fused prep: rmsnorm | cvt(w_qkv) | cvt(w_out) | sincos ----------------
__global__ __launch_bounds__(256) void prep_kernel(const float* __restrict__ x,
                                                   const float* __restrict__ gamma,
                                                   ushort_t* __restrict__ xn,
                                                   const float* __restrict__ w_qkv,
                                                   ushort_t* __restrict__ wq,
                                                   const float* __restrict__ w_out,
                                                   ushort_t* __restrict__ wo,
                                                   float* __restrict__ sint,
                                                   float* __restrict__ cost) {
    int blk = blockIdx.x;
    if (blk < 1024) {
        int wave = threadIdx.x >> 6, lane = threadIdx.x & 63;
        int t = blk * 4 + wave;
        const float* xr = x + (size_t)t * D_MODEL;
        float v[12]; float ss = 0.f;
        #pragma unroll
        for (int j = 0; j < 12; ++j) { v[j] = xr[lane + j*64]; ss += v[j]*v[j]; }
        #pragma unroll
        for (int m = 1; m < 64; m <<= 1) ss += __shfl_xor(ss, m, 64);
        float r = rsqrtf(ss * (1.f/768.f) + 1e-6f);
        ushort_t* o = xn + (size_t)t * D_MODEL;
        #pragma unroll
        for (int j = 0; j < 12; ++j) o[lane + j*64] = f2bf(v[j] * r * gamma[lane + j*64]);
    } else if (blk < 2752) {
        int i = (blk - 1024) * 1024 + threadIdx.x * 4;
        float4 v = *(const float4*)&w_qkv[i];
        uint2 pk; pk.x = cvtpk(v.x, v.y); pk.y = cvtpk(v.z, v.w);
        *(uint2*)&wq[i] = pk;
    } else if (blk < 3328) {
        int i = (blk - 2752) * 1024 + threadIdx.x * 4;
        float4 v = *(const float4*)&w_out[i];
        uint2 pk; pk.x = cvtpk(v.x, v.y); pk.y = cvtpk(v.z, v.w);
        *(uint2*)&wo[i] = pk;
    } else {
        int i = (blk - 3328) * 256 + threadIdx.x;
        int p = i >> 5, j = i & 31;
        int r = p >> 5, c = p & 31;
        int jj = j & 15;
        float freq = powf(10000.f, -(float)(2*jj) / 32.f);
        float pos = (j < 16) ? (float)r : (float)c;
        float th = pos * freq;
        sint[i] = sinf(th);
        cost[i] = cosf(th);
    }
}

// ---------------- 128x128 GEMM, BK=64, 2 buffers, 1 barrier/step, depth-1 prefetch ----------------
template<int NTILES, int EPI>
__global__ __launch_bounds__(256, 2) void gemm128(const ushort_t* __restrict__ A,
                                                  const ushort_t* __restrict__ B,
                                                  const float* __restrict__ sint,
                                                  const float* __restrict__ cost,
                                                  ushort_t* __restrict__ Qr,
                                                  ushort_t* __restrict__ Kr,
                                                  ushort_t* __restrict__ VTt,
                                                  float* __restrict__ C) {
    __shared__ ushort_t As[2][128*64];
    __shared__ ushort_t Bs[2][128*64];
    const int K = 768;
    constexpr int NR = NTILES / 2;
    int c = blockIdx.x & 7;
    int l = blockIdx.x >> 3;
    int mtile = (c >> 1)*8 + l / NR;
    int ntile = (c & 1)*NR + l % NR;
    int tm = mtile * 128, tn = ntile * 128;
    int w = threadIdx.x >> 6, lane = threadIdx.x & 63;
    int wr = w >> 1, wc = w & 1;
    int l15 = lane & 15, l4 = lane >> 4;

    const ushort_t* mat = (w < 2) ? A : B;
    int mbase = (w < 2) ? tm : tn;
    ushort_t* lds_half = (w < 2) ? &As[0][0] : &Bs[0][0];
    int r0w = (w & 1) * 64;
    int srow = r0w + (lane >> 3);
    int sslot = (lane & 7) ^ (srow & 7);
    const ushort_t* gsrc0 = mat + (size_t)(mbase + srow)*K + sslot*8;

    auto stage = [&](int buf, int kstep) {
        int k0 = kstep * 64;
        #pragma unroll
        for (int j = 0; j < 8; ++j) {
            const ushort_t* g = gsrc0 + (size_t)(j*8)*K + k0;
            __builtin_amdgcn_global_load_lds((const __attribute__((address_space(1))) void*)g,
                (__attribute__((address_space(3))) void*)(lds_half + (size_t)buf*8192 + (r0w + j*8)*64),
                16, 0, 0);
        }
    };

    f32x4 acc[4][4] = {};
    auto compute = [&](int bi) {
        short8 af[4][2], bfx[4][2];
        #pragma unroll
        for (int mi = 0; mi < 4; ++mi) {
            int row = wr*64 + mi*16 + l15;
            #pragma unroll
            for (int kk = 0; kk < 2; ++kk)
                af[mi][kk] = *(const short8*)&As[bi][row*64 + ((kk*4 + l4) ^ (row & 7))*8];
        }
        #pragma unroll
        for (int ni = 0; ni < 4; ++ni) {
            int row = wc*64 + ni*16 + l15;
            #pragma unroll
            for (int kk = 0; kk < 2; ++kk)
                bfx[ni][kk] = *(const short8*)&Bs[bi][row*64 + ((kk*4 + l4) ^ (row & 7))*8];
        }
        #pragma unroll
        for (int kk = 0; kk < 2; ++kk)
            #pragma unroll
            for (int mi = 0; mi < 4; ++mi)
                #pragma unroll
                for (int ni = 0; ni < 4; ++ni)
                    acc[mi][ni] = __builtin_amdgcn_mfma_f32_16x16x32_bf16(af[mi][kk], bfx[ni][kk], acc[mi][ni], 0, 0, 0);
    };

    stage(0, 0);
    for (int t = 0; t < 12; ++t) {
        asm volatile("s_waitcnt vmcnt(0)" ::: "memory");
        __builtin_amdgcn_s_barrier();
        if (t < 11) stage((t + 1) & 1, t + 1);
        compute(t & 1);
    }

    if constexpr (EPI == 0) {
        int col_base = tn + wc*64;
        int region = col_base / 768;
        int h = (col_base % 768) >> 6;
        if (region < 2) {
            ushort_t* dst = (region == 0) ? Qr : Kr;
            float scale = (region == 0) ? QSCALE : 1.f;
            #pragma unroll
            for (int mi = 0; mi < 4; ++mi) {
                #pragma unroll
                for (int ni = 0; ni < 2; ++ni) {
                    int d = ni*16 + l15;
                    #pragma unroll
                    for (int r = 0; r < 4; ++r) {
                        int pt = tm + wr*64 + mi*16 + l4*4 + r;
                        int b = pt >> 10, p = pt & 1023;
                        float s = sint[p*32 + d], cc = cost[p*32 + d];
                        float t0 = acc[mi][ni][r], t1 = acc[mi][ni+2][r];
                        size_t o = (size_t)(b*NHEAD + h)*HW*HD + (size_t)p*HD + d;
                        dst[o]      = f2bf((t0*cc - t1*s) * scale);
                        dst[o + 32] = f2bf((t1*cc + t0*s) * scale);
                    }
                }
            }
        } else {
            #pragma unroll
            for (int mi = 0; mi < 4; ++mi) {
                int pt = tm + wr*64 + mi*16 + l4*4;
                int b = pt >> 10, p = pt & 1023;
                size_t hb = (size_t)(b*NHEAD + h)*HD*HW;
                #pragma unroll
                for (int ni = 0; ni < 4; ++ni) {
                    int d = ni*16 + l15;
                    ushort4_t pk;
                    pk.x = f2bf(acc[mi][ni][0]);
                    pk.y = f2bf(acc[mi][ni][1]);
                    pk.z = f2bf(acc[mi][ni][2]);
                    pk.w = f2bf(acc[mi][ni][3]);
                    *(ushort4_t*)&VTt[hb + (size_t)d*HW + p] = pk;
                }
            }
        }
    } else {
        #pragma unroll
        for (int mi = 0; mi < 4; ++mi)
            #pragma unroll
            for (int ni = 0; ni < 4; ++ni)
                #pragma unroll
                for (int r = 0; r < 4; ++r) {
                    int row = tm + wr*64 + mi*16 + l4*4 + r;
                    int col = tn + wc*64 + ni*16 + l15;
                    C[(size_t)row*(128*NTILES) + col] = acc[mi][ni][r];
                }
    }
}

// ---------------- flash attention: R16 structure + deferred lsum reduction ----------------
// grid 768 (16 qtiles x 48 bh, XCD-swizzled); 4 waves; wave: 16 q, kv tiles of 64
__global__ __launch_bounds__(256, 3) void attn_kernel(const ushort_t* __restrict__ Q,
                                                      const ushort_t* __restrict__ Kt,
                                                      const ushort_t* __restrict__ VT,
                                                      ushort_t* __restrict__ Ao) {
    __shared__ ushort_t Kb[2][64*64];
    __shared__ ushort_t Vb[2][64*64];
    __shared__ ushort_t P[4][16][72];
    int flat = blockIdx.x;
    int swz = (flat & 7) * 96 + (flat >> 3);
    int bh = swz >> 4;
    int qtile = swz & 15;
    int w = threadIdx.x >> 6, lane = threadIdx.x & 63;
    int l15 = lane & 15, l4 = lane >> 4;
    int qbase = qtile * 64 + w * 16;
    int q = qbase + l15;
    int qr = q >> 5, qc = q & 31;
    const ushort_t* Qh = Q + (size_t)bh * HW * HD;
    const ushort_t* Kh = Kt + (size_t)bh * HW * HD;
    const ushort_t* Vh = VT + (size_t)bh * HD * HW;
    short8 aq0 = *(const short8*)&Qh[(size_t)q*64 + l4*8];
    short8 aq1 = *(const short8*)&Qh[(size_t)q*64 + 32 + l4*8];
    unsigned pat = (qc == 0) ? 3u : (7u << (qc - 1));
    float m = -1e30f, lsum = 0.f;   // lsum: per-lane partial (reduced once after the loop)
    f32x4 oacc[4] = {};

    auto stage = [&](int bufi, int kv) {
        #pragma unroll
        for (int is = 0; is < 2; ++is) {
            int c = is*256 + w*64 + lane;
            int row = c >> 3;
            int col16 = (c & 7) ^ (row & 7);
            const ushort_t* ga = Kh + (size_t)(kv + row)*64 + col16*8;
            __builtin_amdgcn_global_load_lds((const __attribute__((address_space(1))) void*)ga,
                (__attribute__((address_space(3))) void*)(&Kb[bufi][(size_t)(is*256 + w*64)*8]), 16, 0, 0);
            const ushort_t* gv = Vh + (size_t)row*HW + kv + col16*8;
            __builtin_amdgcn_global_load_lds((const __attribute__((address_space(1))) void*)gv,
                (__attribute__((address_space(3))) void*)(&Vb[bufi][(size_t)(is*256 + w*64)*8]), 16, 0, 0);
        }
    };

    stage(0, 0);

    for (int t = 0; t < 16; ++t) {
        asm volatile("s_waitcnt vmcnt(0)" ::: "memory");
        __builtin_amdgcn_s_barrier();
        if (t < 15) stage((t + 1) & 1, (t + 1) * 64);
        int cur = t & 1;
        int kv = t * 64;
        int sw = l15 & 7;
        f32x4 s[4];
        __builtin_amdgcn_s_setprio(1);
        #pragma unroll
        for (int st = 0; st < 4; ++st) {
            int krow = st*16 + l15;
            short8 bk0 = *(const short8*)&Kb[cur][(size_t)krow*64 + (size_t)((l4 ^ sw))*8];
            short8 bk1 = *(const short8*)&Kb[cur][(size_t)krow*64 + (size_t)(((4+l4) ^ sw))*8];
            f32x4 z = {};
            z = __builtin_amdgcn_mfma_f32_16x16x32_bf16(bk0, aq0, z, 0, 0, 0);
            z = __builtin_amdgcn_mfma_f32_16x16x32_bf16(bk1, aq1, z, 0, 0, 0);
            s[st] = z;
        }
        __builtin_amdgcn_s_setprio(0);
        short8 va0[4], va1[4];
        #pragma unroll
        for (int dt = 0; dt < 4; ++dt) {
            int vrow = dt*16 + l15;
            va0[dt] = *(const short8*)&Vb[cur][(size_t)vrow*64 + (size_t)((l4 ^ sw))*8];
            va1[dt] = *(const short8*)&Vb[cur][(size_t)vrow*64 + (size_t)(((4+l4) ^ sw))*8];
        }
        int dr = qr - (kv >> 5);
        if (dr >= -1 && dr <= 2) {
            u64 tm = 0;
            if (dr <= 1) tm |= (u64)pat;
            if (dr >= 0) tm |= ((u64)pat) << 32;
            u64 sub = tm >> (l4*4);
            #pragma unroll
            for (int st = 0; st < 4; ++st)
                #pragma unroll
                for (int i = 0; i < 4; ++i)
                    if ((sub >> (st*16 + i)) & 1) s[st][i] = -1e30f;
        }
        // ---- max: max3-friendly tree + 2 shuffles ----
        float vmax = fmaxf(
            fmaxf(fmaxf(fmaxf(s[0][0], s[0][1]), s[0][2]),
                  fmaxf(fmaxf(s[0][3], s[1][0]), s[1][1])),
            fmaxf(fmaxf(fmaxf(s[1][2], s[1][3]), fmaxf(s[2][0], s[2][1])),
                  fmaxf(fmaxf(fmaxf(s[2][2], s[2][3]), fmaxf(s[3][0], s[3][1])),
                        fmaxf(s[3][2], s[3][3]))));
        vmax = fmaxf(vmax, __shfl_xor(vmax, 16, 64));
        vmax = fmaxf(vmax, __shfl_xor(vmax, 32, 64));
        if (__any(vmax - m > 8.f)) {
            float mn = fmaxf(m, vmax);
            float sf = ex2(m - mn);   // row-uniform: all 4 lanes of a row share m, mn
            lsum *= sf;
            #pragma unroll
            for (int dt = 0; dt < 4; ++dt)
                #pragma unroll
                for (int i = 0; i < 4; ++i) oacc[dt][i] *= sf;
            m = mn;
        }
        // ---- P = 2^(s-m); per-lane partial row-sum (reduction deferred) ----
        #pragma unroll
        for (int st = 0; st < 4; ++st) {
            float p0 = ex2(s[st][0] - m), p1 = ex2(s[st][1] - m);
            float p2 = ex2(s[st][2] - m), p3 = ex2(s[st][3] - m);
            lsum += (p0 + p1) + (p2 + p3);
            uint2 pk;
            pk.x = cvtpk(p0, p1);
            pk.y = cvtpk(p2, p3);
            *(uint2*)&P[w][l15][st*16 + l4*4] = pk;
        }
        short8 pf0 = *(const short8*)&P[w][l15][l4*8];
        short8 pf1 = *(const short8*)&P[w][l15][32 + l4*8];
        __builtin_amdgcn_s_setprio(1);
        #pragma unroll
        for (int dt = 0; dt < 4; ++dt) {
            oacc[dt] = __builtin_amdgcn_mfma_f32_16x16x32_bf16(va0[dt], pf0, oacc[dt], 0, 0, 0);
            oacc[dt] = __builtin_amdgcn_mfma_f32_16x16x32_bf16(va1[dt], pf1, oacc[dt], 0, 0, 0);
        }
        __builtin_amdgcn_s_setprio(0);
    }
    // ---- final lsum reduction across the row's 4 lane-groups ----
    lsum += __shfl_xor(lsum, 16, 64);
    lsum += __shfl_xor(lsum, 32, 64);
    int b = bh / NHEAD, h = bh % NHEAD;
    float rl = 1.f / lsum;
    size_t obase = ((size_t)b*HW + q)*D_MODEL + h*64;
    #pragma unroll
    for (int dt = 0; dt < 4; ++dt) {
        uint2 pk;
        pk.x = cvtpk(oacc[dt][0]*rl, oacc[dt][1]*rl);
        pk.y = cvtpk(oacc[dt][2]*rl, oacc[dt][3]*rl);
        *(uint2*)&Ao[obase + dt*16 + l4*4] = pk;
    }
}

extern "C" void kernel_launch(void* const* d_in, const int* in_sizes, int n_in,
                              void* d_out, int out_size, void* d_ws, size_t ws_size,
                              hipStream_t stream) {
    const float* x      = (const float*)d_in[0];
    const float* w_qkv  = (const float*)d_in[1];
    const float* w_out  = (const float*)d_in[2];
    const float* gamma  = (const float*)d_in[3];
    float* out = (float*)d_out;

    char* ws = (char*)d_ws;
    size_t off = 0;
    auto alloc = [&](size_t bytes) { char* p = ws + off; off += (bytes + 255) & ~255ull; return p; };
    ushort_t* xn   = (ushort_t*)alloc((size_t)TOK*D_MODEL*2);
    ushort_t* wq   = (ushort_t*)alloc((size_t)QKV_N*D_MODEL*2);
    ushort_t* wo   = (ushort_t*)alloc((size_t)D_MODEL*D_MODEL*2);
    float* sint    = (float*)alloc((size_t)HW*32*4);
    float* cost    = (float*)alloc((size_t)HW*32*4);
    ushort_t* Qr   = (ushort_t*)alloc((size_t)BH*HW*HD*2);
    ushort_t* Kr   = (ushort_t*)alloc((size_t)BH*HW*HD*2);
    ushort_t* VTt  = (ushort_t*)alloc((size_t)BH*HD*HW*2);
    ushort_t* Ao   = (ushort_t*)alloc((size_t)TOK*D_MODEL*2);

    prep_kernel<<<3456, 256, 0, stream>>>(x, gamma, xn, w_qkv, wq, w_out, wo, sint, cost);
    gemm128<18,0><<<576, 256, 0, stream>>>(xn, wq, sint, cost, Qr, Kr, VTt, nullptr);
    attn_kernel<<<768, 256, 0, stream>>>(Qr, Kr, VTt, Ao);
    gemm128<6,1><<<192, 256, 0, stream>>>(Ao, wo, nullptr, nullptr, nullptr, nullptr, nullptr, out);
}